// Round 11
// baseline (349.090 us; speedup 1.0000x reference)
//
#include <hip/hip_runtime.h>
#include <hip/hip_bf16.h>
#include <math.h>

// Problem constants
#define Ln     35
#define CINn   21
#define CINP   24        // padded CIN (multiple of 8 -> aligned b128 im2col reads)
#define Fn     128
#define Kn     9
#define Hn     64
#define GB     16        // batch rows per block
#define SEQ_STRIDE 1064  // 44 rows*24 + 8 slack (shorts); l=35 window ends exactly at 1064
#define TILE_STRIDE 136  // 128 + 8 pad (shorts)
#define YP_STRIDE 136    // floats per l-row in s_yp: 8 n-tiles*16 batch + 8 pad
#define NYL    16        // s_yp rows: l in [10,25] only

typedef __attribute__((ext_vector_type(8))) short short8;
typedef __attribute__((ext_vector_type(4))) float f32x4;

static __device__ __forceinline__ unsigned short bf16bits(float f) {
    __hip_bfloat16 h = __float2bfloat16(f);
    return *(unsigned short*)&h;
}

// f32 lane-row (16-lane) sum via DPP rotate-accumulate: VALU pipe, zero LDS traffic.
template <int CTRL>
static __device__ __forceinline__ float dpp_add(float v) {
    int r = __builtin_amdgcn_update_dpp(0, __builtin_bit_cast(int, v),
                                        CTRL, 0xF, 0xF, true);
    return v + __builtin_bit_cast(float, r);
}
static __device__ __forceinline__ float row_sum16(float v) {
    v = dpp_add<0x128>(v);   // ror 8
    v = dpp_add<0x124>(v);   // ror 4
    v = dpp_add<0x122>(v);   // ror 2
    v = dpp_add<0x121>(v);   // ror 1
    return v;
}

// ---------------- single fused kernel: 16 batch rows / block, 512 threads ----------------
// 8 waves/block. CONV: wave w owns f-tile [16w,16w+16) for BOTH l of the stage.
// MLP (l-split, round-11): wave w owns ONE l = l0 + (w>>2) and TWO n-tiles
// {2(w&3), 2(w&3)+1} (tiles 0-3 = n-head, 4-7 = c-head; head uniform per wave).
// This halves MLP LDS reads (am[4] for one l instead of am0+am1 for two).
// STRUCTURE RULES (rounds 1-10):
//  * Occupancy is REGISTER-bound at 128 unified regs/wave (launch_bounds(512,4) ->
//    4 waves/SIMD = 16 waves/CU = 2 blocks). LDS size does NOT move occupancy
//    (42% at both 70.6KB and 51.7KB). Budget every edit against 128 total.
//  * Uniform loop, explicit fragment arrays, block-uniform guards, no escaping
//    values. Gate every structural edit on WRITE_SIZE == 128 KiB.
//  * Conv b128 bank pattern is at the wave64 floor; don't swizzle.
// Register funding for the +16 w1b regs: conv chains run SEQUENTIALLY with one
// reused af[7] (28 transient instead of af0+af1's 56), fenced by sched_barrier(0)
// between chains and at loop end so the scheduler can't overlap fragment liveness.
// Sync cadence: r8-proven 4-slot ring, ONE barrier per MLP stage (WAR distance 2).
__global__ __launch_bounds__(512, 4) void fused_kernel(
    const float* __restrict__ seq,    const int*   __restrict__ plen_arr,
    const float* __restrict__ conv_w, const float* __restrict__ conv_b,
    const float* __restrict__ n_w1,   const float* __restrict__ n_b1,
    const float* __restrict__ n_w2,   const float* __restrict__ n_b2,
    const float* __restrict__ c_w1,   const float* __restrict__ c_b1,
    const float* __restrict__ c_w2,   const float* __restrict__ c_b2,
    const float* __restrict__ navg_w, const float* __restrict__ navg_b,
    const float* __restrict__ cavg_w, const float* __restrict__ cavg_b,
    const float* __restrict__ out_w,  const float* __restrict__ out_b,
    float* __restrict__ out)
{
    __shared__ __align__(16) unsigned short s_seq[GB * SEQ_STRIDE];      // 34048 B
    __shared__ __align__(16) unsigned short s_tile[4][GB * TILE_STRIDE]; // 17408 B
    __shared__ __align__(16) float s_yp[NYL * YP_STRIDE];                //  8704 B: [l-10][tile*16+m]
    // overlays on s_seq (dead after the main loop):
    float* s_y   = (float*)s_seq;            // [2][GB][36] = 1152 floats
    float* s_avg = (float*)s_seq + 1152;     // [8 waves][2][GB] = 256 floats

    const int t    = threadIdx.x;
    const int wave = t >> 6;                 // 0..7
    const int lane = t & 63;
    const int quad = lane >> 4;
    const int col  = lane & 15;
    const int b0   = blockIdx.x * GB;
    const int lsel = wave >> 2;              // MLP: which l of the stage pair
    const int t0   = 2 * (wave & 3);         // MLP: first of two n-tiles

    // ---- zero-init padded seq (pad rows/channels + slack must be 0) ----
    {
        uint4* p = (uint4*)s_seq;            // 34048/16 = 2128 uint4
        for (int i = t; i < (GB * SEQ_STRIDE) / 8; i += 512)
            p[i] = make_uint4(0u, 0u, 0u, 0u);
    }

    // ---- per-lane loop-invariant weight fragments ----
    // conv A-frag (operand-swapped): A[m=f=16*wave+col][k=kk], kk = k*24+c
    // MLP  B-frags for tiles t0,t0+1: B[k=f][n]
    short8 wb[7];
    short8 w1b[2][4];
    float  cbias[4], b1v[2], w2v[2];
    {
        const int ng = wave * 16 + col;      // conv f (A m-index)
        #pragma unroll
        for (int s = 0; s < 7; s++) {
            short8 v;
            #pragma unroll
            for (int j = 0; j < 8; j++) {
                int kk = 32 * s + quad * 8 + j;
                int k = kk / CINP, c = kk % CINP;
                float f = (k < Kn && c < CINn) ? conv_w[(k * CINn + c) * Fn + ng] : 0.0f;
                v[j] = (short)bf16bits(f);
            }
            wb[s] = v;
        }
        #pragma unroll
        for (int j = 0; j < 2; j++) {
            const int nt = t0 + j;           // n-tile 0..7
            const int nl = (nt * 16 + col) & 63;
            const int hj = nt >= 4;          // wave-uniform (both tiles same head)
            #pragma unroll
            for (int s = 0; s < 4; s++) {
                short8 v;
                #pragma unroll
                for (int jj = 0; jj < 8; jj++) {
                    int k = 32 * s + quad * 8 + jj;
                    float f = hj ? c_w1[k * Hn + nl] : n_w1[k * Hn + nl];
                    v[jj] = (short)bf16bits(f);
                }
                w1b[j][s] = v;
            }
            b1v[j] = hj ? c_b1[nl] : n_b1[nl];
            w2v[j] = hj ? c_w2[nl] : n_w2[nl];
        }
        #pragma unroll
        for (int r = 0; r < 4; r++)
            cbias[r] = conv_b[wave * 16 + 4 * quad + r];
    }
    const int plen_lane = plen_arr[b0 + col];   // this lane's batch (=col) plen

    __syncthreads();   // zero-init done before data fill

    // ---- stage seq -> bf16 LDS, rows shifted +4 (SAME pad), c<21 only ----
    // float4 global loads; element (bi,l,c) -> bi*1064 + (4+l)*24 + c. For a float4
    // at r = l*21+c, element j: row wrap (+3), batch wrap (+224 more). (r10-verified)
    {
        const float4* gsrc = (const float4*)(seq + (size_t)b0 * (Ln * CINn));
        for (int i = t; i < (GB * Ln * CINn) / 4; i += 512) {
            int i4 = i * 4;
            int bi = i4 / (Ln * CINn), r = i4 - bi * (Ln * CINn);
            int l = r / CINn, c = r - l * CINn;
            float4 v = gsrc[i];
            int base = bi * SEQ_STRIDE + (4 + l) * CINP + c;
            #pragma unroll
            for (int j = 0; j < 4; j++) {
                float fj = (j == 0) ? v.x : (j == 1) ? v.y : (j == 2) ? v.z : v.w;
                int adj = ((c + j >= CINn) ? 3 : 0) + ((r + j >= Ln * CINn) ? 224 : 0);
                s_seq[base + j + adj] = bf16bits(fj);
            }
        }
    }
    __syncthreads();

    float sum_n[4] = {0.f,0.f,0.f,0.f};
    float sum_c[4] = {0.f,0.f,0.f,0.f};

    // ---- main loop: 2 l per stage, 18 stages. MLP section (1 barrier) only in the
    // 8 stages with l0 in [10,26). 4-slot ring on s_tile: stage writes {l0&3,l1&3};
    // next rewrite of a slot is 2 stages (>=1 barrier) later -> WAR safe (r8-proven).
    for (int l0 = 0; l0 < 36; l0 += 2) {
        const int l1 = l0 + 1;
        // ---- conv GEMM, sequential chains with ONE af[7] (register funding) ----
        f32x4 cacc0 = {0.f,0.f,0.f,0.f};
        {
            short8 af[7];
            #pragma unroll
            for (int s = 0; s < 7; s++)
                af[s] = *(const short8*)&s_seq[col * SEQ_STRIDE + l0 * CINP + 32 * s + quad * 8];
            #pragma unroll
            for (int s = 0; s < 7; s++)
                cacc0 = __builtin_amdgcn_mfma_f32_16x16x32_bf16(wb[s], af[s], cacc0, 0, 0, 0);
        }
        __builtin_amdgcn_sched_barrier(0);   // end af(l0) liveness before af(l1) loads
        f32x4 cacc1 = {0.f,0.f,0.f,0.f};
        {
            short8 af[7];
            #pragma unroll
            for (int s = 0; s < 7; s++)
                af[s] = *(const short8*)&s_seq[col * SEQ_STRIDE + l1 * CINP + 32 * s + quad * 8];
            #pragma unroll
            for (int s = 0; s < 7; s++)
                cacc1 = __builtin_amdgcn_mfma_f32_16x16x32_bf16(wb[s], af[s], cacc1, 0, 0, 0);
        }
        __builtin_amdgcn_sched_barrier(0);
        // ---- epilogue: lane holds batch=col, f = 16*wave + 4q + r ----
        float a0 = fmaxf(cacc0[0] + cbias[0], 0.0f);
        float a1 = fmaxf(cacc0[1] + cbias[1], 0.0f);
        float a2 = fmaxf(cacc0[2] + cbias[2], 0.0f);
        float a3 = fmaxf(cacc0[3] + cbias[3], 0.0f);
        float e0 = fmaxf(cacc1[0] + cbias[0], 0.0f);
        float e1 = fmaxf(cacc1[1] + cbias[1], 0.0f);
        float e2 = fmaxf(cacc1[2] + cbias[2], 0.0f);
        float e3 = fmaxf(cacc1[3] + cbias[3], 0.0f);
        {
            float cm0 = (l0 >= 10 + plen_lane && l0 < 20 + plen_lane) ? 1.0f : 0.0f;
            float cm1 = (l1 >= 10 + plen_lane && l1 < 20 + plen_lane) ? 1.0f : 0.0f;
            if (l0 < 10) {            // wave-uniform
                sum_n[0] += a0; sum_n[1] += a1; sum_n[2] += a2; sum_n[3] += a3;
            }
            if (l1 < 10) {
                sum_n[0] += e0; sum_n[1] += e1; sum_n[2] += e2; sum_n[3] += e3;
            }
            sum_c[0] += cm0 * a0 + cm1 * e0;
            sum_c[1] += cm0 * a1 + cm1 * e1;
            sum_c[2] += cm0 * a2 + cm1 * e2;
            sum_c[3] += cm0 * a3 + cm1 * e3;
        }

        // ---- MLP section: only for l whose y is consumed (l in [10,25]) ----
        if (l0 >= 10 && l0 < 26) {           // block-uniform; barrier inside is legal
            ushort4 pk0 = { bf16bits(a0), bf16bits(a1), bf16bits(a2), bf16bits(a3) };
            ushort4 pk1 = { bf16bits(e0), bf16bits(e1), bf16bits(e2), bf16bits(e3) };
            *(ushort4*)&s_tile[l0 & 3][col * TILE_STRIDE + wave * 16 + 4 * quad] = pk0;
            *(ushort4*)&s_tile[l1 & 3][col * TILE_STRIDE + wave * 16 + 4 * quad] = pk1;
            __syncthreads();   // conv tiles written -> MLP may read; ring WAR fence

            // ---- l-split MLP: this wave's l, am[4] covers K=128 f once ----
            const int myl = l0 + lsel;
            short8 am[4];
            #pragma unroll
            for (int s = 0; s < 4; s++)
                am[s] = *(const short8*)&s_tile[myl & 3][col * TILE_STRIDE + 32 * s + quad * 8];
            f32x4 h0 = {0.f,0.f,0.f,0.f};
            f32x4 h1 = {0.f,0.f,0.f,0.f};
            #pragma unroll
            for (int s = 0; s < 4; s++) {
                h0 = __builtin_amdgcn_mfma_f32_16x16x32_bf16(am[s], w1b[0][s], h0, 0, 0, 0);
                h1 = __builtin_amdgcn_mfma_f32_16x16x32_bf16(am[s], w1b[1][s], h1, 0, 0, 0);
            }
            // ---- y partial = relu(h+b1) @ w2 per tile; DPP row-sum over 16 n ----
            float p0[4], p1[4];
            #pragma unroll
            for (int r = 0; r < 4; r++) {
                p0[r] = row_sum16(fmaxf(h0[r] + b1v[0], 0.f) * w2v[0]);
                p1[r] = row_sum16(fmaxf(h1[r] + b1v[1], 0.f) * w2v[1]);
            }
            if (col == 0) {                  // batch index = 4*quad + r
                const int rowb = (myl - 10) * YP_STRIDE;
                *(f32x4*)&s_yp[rowb + t0 * 16 + quad * 4] =
                    (f32x4){p0[0], p0[1], p0[2], p0[3]};
                *(f32x4*)&s_yp[rowb + (t0 + 1) * 16 + quad * 4] =
                    (f32x4){p1[0], p1[1], p1[2], p1[3]};
            }
        }
        __builtin_amdgcn_sched_barrier(0);   // no cross-iteration fragment overlap
    }
    __syncthreads();   // all s_seq reads done -> overlay safe; s_yp complete

    // ---- flank-average partials: apply navg_w/cavg_w post-loop ----
    {
        float an = 0.f, ac = 0.f;
        #pragma unroll
        for (int r = 0; r < 4; r++) {
            int fidx = wave * 16 + 4 * quad + r;
            an += sum_n[r] * navg_w[fidx];
            ac += sum_c[r] * cavg_w[fidx];
        }
        an += __shfl_xor(an, 16); an += __shfl_xor(an, 32);   // sum over quads
        ac += __shfl_xor(ac, 16); ac += __shfl_xor(ac, 32);
        if (quad == 0) {                     // lane < 16: one per batch
            s_avg[wave * 2 * GB + 0 * GB + col] = an;
            s_avg[wave * 2 * GB + 1 * GB + col] = ac;
        }
    }
    __syncthreads();

    // ---- y finalize: y = tanh(sum of 4 tile-partials + b2), l in [10,25] (512 vals) ----
    // m-fastest decomposition: 64 lanes cover all 32 banks 2-way (conflict-free).
    {
        const float bn = n_b2[0], bc = c_b2[0];
        for (int i = t; i < 2 * GB * NYL; i += 512) {
            int m = i & 15, rem = i >> 4;        // rem = 0..31
            int li = rem & 15, hd = rem >> 4;    // li = l-10
            float v = (hd ? bc : bn);
            #pragma unroll
            for (int w = 0; w < 4; w++)
                v += s_yp[li * YP_STRIDE + (hd * 4 + w) * 16 + m];
            s_y[hd * GB * 36 + m * 36 + (10 + li)] = tanhf(v);
        }
    }
    __syncthreads();

    // ---- final combine: one thread per batch row ----
    if (t < GB) {
        const int m = t;
        const int plen = plen_arr[b0 + m];
        const float* ym = s_y + m * 36;               // n-head row
        const float* yc = s_y + GB * 36 + m * 36;     // c-head row
        float cleaved_n = ym[10];
        float mn = 0.f;   // reference maxes (y+1)*mask over ALL l; unmasked give 0
        for (int l = 11; l < 10 + plen; l++) mn = fmaxf(mn, ym[l] + 1.f);
        float maxpool_n = -(mn - 1.f);
        float cleaved_c = yc[10 + plen - 1];
        float mc = 0.f;
        for (int l = 10; l < 10 + plen - 1; l++) mc = fmaxf(mc, yc[l] + 1.f);
        float maxpool_c = -(mc - 1.f);
        float sn = 0.f, sc = 0.f;
        #pragma unroll
        for (int w = 0; w < 8; w++) {
            sn += s_avg[w * 2 * GB + 0 * GB + m];
            sc += s_avg[w * 2 * GB + 1 * GB + m];
        }
        float avg_n = tanhf(sn * 0.1f + navg_b[0]);
        float avg_c = tanhf(sc * 0.1f + cavg_b[0]);
        float comb = cleaved_n * out_w[0] + maxpool_n * out_w[1] + avg_n * out_w[2]
                   + cleaved_c * out_w[3] + maxpool_c * out_w[4] + avg_c * out_w[5]
                   + out_b[0];
        out[b0 + m] = 1.f / (1.f + expf(-comb));
    }
}

extern "C" void kernel_launch(void* const* d_in, const int* in_sizes, int n_in,
                              void* d_out, int out_size, void* d_ws, size_t ws_size,
                              hipStream_t stream) {
    const int B = in_sizes[1];
    fused_kernel<<<B / GB, 512, 0, stream>>>(
        (const float*)d_in[0],  (const int*)d_in[1],
        (const float*)d_in[2],  (const float*)d_in[3],
        (const float*)d_in[4],  (const float*)d_in[5],
        (const float*)d_in[6],  (const float*)d_in[7],
        (const float*)d_in[8],  (const float*)d_in[9],
        (const float*)d_in[10], (const float*)d_in[11],
        (const float*)d_in[12], (const float*)d_in[13],
        (const float*)d_in[14], (const float*)d_in[15],
        (const float*)d_in[16], (const float*)d_in[17],
        (float*)d_out);
}

// Round 12
// 304.876 us; speedup vs baseline: 1.1450x; 1.1450x over previous
//
#include <hip/hip_runtime.h>
#include <hip/hip_bf16.h>
#include <math.h>

// Problem constants
#define Ln     35
#define CINn   21
#define CINP   24        // padded CIN (multiple of 8 -> aligned b128 im2col reads)
#define Fn     128
#define Kn     9
#define Hn     64
#define GB     16        // batch rows per block
#define SEQ_STRIDE 1064  // 44 rows*24 + 8 slack (shorts); l=35 window ends exactly at 1064
#define TILE_STRIDE 136  // 128 + 8 pad (shorts)
#define YP_STRIDE 136    // floats per l-row in s_yp: 8 waves*16 batch + 8 pad
#define NYL    16        // s_yp rows: l in [10,25] only

typedef __attribute__((ext_vector_type(8))) short short8;
typedef __attribute__((ext_vector_type(4))) float f32x4;

static __device__ __forceinline__ unsigned short bf16bits(float f) {
    __hip_bfloat16 h = __float2bfloat16(f);
    return *(unsigned short*)&h;
}

// f32 lane-row (16-lane) sum via DPP rotate-accumulate: VALU pipe, zero LDS traffic.
template <int CTRL>
static __device__ __forceinline__ float dpp_add(float v) {
    int r = __builtin_amdgcn_update_dpp(0, __builtin_bit_cast(int, v),
                                        CTRL, 0xF, 0xF, true);
    return v + __builtin_bit_cast(float, r);
}
static __device__ __forceinline__ float row_sum16(float v) {
    v = dpp_add<0x128>(v);   // ror 8
    v = dpp_add<0x124>(v);   // ror 4
    v = dpp_add<0x122>(v);   // ror 2
    v = dpp_add<0x121>(v);   // ror 1
    return v;
}

// ---------------- single fused kernel: 16 batch rows / block, 512 threads ----------------
// 8 waves/block; wave w owns conv f-tile [16w,16w+16) and MLP n-tile [16w,16w+16)
// (n<64 = n-head, n>=64 = c-head). Weight frags per wave: 28+16 = 44 VGPRs.
// STRUCTURE RULES (rounds 1-11, final form):
//  * Occupancy is REGISTER-bound at the 128 unified regs/wave cap (2 blocks/CU, 42%
//    at any LDS size). EVERY attempt to restructure register allocation spilled:
//    region peeling (r1-3), 4-wave/2-tile (r4), shared conv reads (r6,r7),
//    l-split MLP +16 regs (r11). Only register-neutral, shape-preserving edits land.
//  * Uniform 18-stage loop, explicit af0[7]/af1[7] arrays, block-uniform guards with
//    no escaping values. Gate every edit on WRITE_SIZE == 128 KiB.
//  * Conv b128 bank pattern is at the wave64 floor; don't swizzle.
// Round-12 delta: revert r10's 2-slot ring (2 barriers/stage) to the r8-proven
// 4-slot ring with ONE barrier per MLP stage. WAR safety: stage i's reads complete
// before barrier i+1, slot rewrite is in stage i+2 -> read < B(i+1) < rewrite; all
// MLP stages are contiguous so every intervening stage carries a barrier.
// Removes 8 of 16 in-loop barriers. LDS 51.7 -> 60.4 KB (no occupancy effect).
__global__ __launch_bounds__(512, 4) void fused_kernel(
    const float* __restrict__ seq,    const int*   __restrict__ plen_arr,
    const float* __restrict__ conv_w, const float* __restrict__ conv_b,
    const float* __restrict__ n_w1,   const float* __restrict__ n_b1,
    const float* __restrict__ n_w2,   const float* __restrict__ n_b2,
    const float* __restrict__ c_w1,   const float* __restrict__ c_b1,
    const float* __restrict__ c_w2,   const float* __restrict__ c_b2,
    const float* __restrict__ navg_w, const float* __restrict__ navg_b,
    const float* __restrict__ cavg_w, const float* __restrict__ cavg_b,
    const float* __restrict__ out_w,  const float* __restrict__ out_b,
    float* __restrict__ out)
{
    __shared__ __align__(16) unsigned short s_seq[GB * SEQ_STRIDE];      // 34048 B
    __shared__ __align__(16) unsigned short s_tile[4][GB * TILE_STRIDE]; // 17408 B
    __shared__ __align__(16) float s_yp[NYL * YP_STRIDE];                //  8704 B: [l-10][wave*16+m]
    // overlays on s_seq (dead after the main loop):
    float* s_y   = (float*)s_seq;            // [2][GB][36] = 1152 floats
    float* s_avg = (float*)s_seq + 1152;     // [8 waves][2][GB] = 256 floats

    const int t    = threadIdx.x;
    const int wave = t >> 6;                 // 0..7
    const int lane = t & 63;
    const int quad = lane >> 4;
    const int col  = lane & 15;
    const int b0   = blockIdx.x * GB;

    // ---- zero-init padded seq (pad rows/channels + slack must be 0) ----
    {
        uint4* p = (uint4*)s_seq;            // 34048/16 = 2128 uint4
        for (int i = t; i < (GB * SEQ_STRIDE) / 8; i += 512)
            p[i] = make_uint4(0u, 0u, 0u, 0u);
    }

    // ---- per-lane loop-invariant weight fragments (single tile per wave) ----
    // conv A-frag (operand-swapped): A[m=f=16*wave+col][k=kk], kk = k*24+c
    // MLP  B-frag: B[k=f][n=16*wave+col]
    short8 wb[7];
    short8 w1b[4];
    float  cbias[4], b1v, w2v;
    const int head = wave >> 2;              // 0 = n-head (waves 0-3), 1 = c (waves 4-7)
    {
        const int ng = wave * 16 + col;      // conv f (A m-index) AND mlp n-index
        #pragma unroll
        for (int s = 0; s < 7; s++) {
            short8 v;
            #pragma unroll
            for (int j = 0; j < 8; j++) {
                int kk = 32 * s + quad * 8 + j;
                int k = kk / CINP, c = kk % CINP;
                float f = (k < Kn && c < CINn) ? conv_w[(k * CINn + c) * Fn + ng] : 0.0f;
                v[j] = (short)bf16bits(f);
            }
            wb[s] = v;
        }
        const int nl = ng & 63;
        #pragma unroll
        for (int s = 0; s < 4; s++) {
            short8 v;
            #pragma unroll
            for (int j = 0; j < 8; j++) {
                int k = 32 * s + quad * 8 + j;
                float f = head ? c_w1[k * Hn + nl] : n_w1[k * Hn + nl];
                v[j] = (short)bf16bits(f);
            }
            w1b[s] = v;
        }
        #pragma unroll
        for (int r = 0; r < 4; r++)
            cbias[r] = conv_b[wave * 16 + 4 * quad + r];
        b1v = head ? c_b1[nl] : n_b1[nl];
        w2v = head ? c_w2[nl] : n_w2[nl];
    }
    const int plen_lane = plen_arr[b0 + col];   // this lane's batch (=col) plen

    __syncthreads();   // zero-init done before data fill

    // ---- stage seq -> bf16 LDS, rows shifted +4 (SAME pad), c<21 only ----
    // float4 global loads; element (bi,l,c) -> bi*1064 + (4+l)*24 + c. For a float4
    // at r = l*21+c, element j: row wrap (+3), batch wrap (+224 more). (r10-verified)
    {
        const float4* gsrc = (const float4*)(seq + (size_t)b0 * (Ln * CINn));
        for (int i = t; i < (GB * Ln * CINn) / 4; i += 512) {
            int i4 = i * 4;
            int bi = i4 / (Ln * CINn), r = i4 - bi * (Ln * CINn);
            int l = r / CINn, c = r - l * CINn;
            float4 v = gsrc[i];
            int base = bi * SEQ_STRIDE + (4 + l) * CINP + c;
            #pragma unroll
            for (int j = 0; j < 4; j++) {
                float fj = (j == 0) ? v.x : (j == 1) ? v.y : (j == 2) ? v.z : v.w;
                int adj = ((c + j >= CINn) ? 3 : 0) + ((r + j >= Ln * CINn) ? 224 : 0);
                s_seq[base + j + adj] = bf16bits(fj);
            }
        }
    }
    __syncthreads();

    float sum_n[4] = {0.f,0.f,0.f,0.f};
    float sum_c[4] = {0.f,0.f,0.f,0.f};

    // ---- main loop: 2 l per stage, 18 stages. MLP section (1 barrier) only in the
    // 8 stages with l0 in [10,26). 4-slot ring on s_tile: stage writes {l0&3,l1&3};
    // rewrite of a slot is 2 stages (and >=1 barrier) later -> WAR safe (r8-proven).
    // l=35 is a computed pad column (auto-masked from sums).
    for (int l0 = 0; l0 < 36; l0 += 2) {
        const int l1 = l0 + 1;
        // ---- conv GEMM (operand-swapped): D^T[f][batch], wave's 16-f tile ----
        short8 af0[7], af1[7];
        #pragma unroll
        for (int s = 0; s < 7; s++) {
            af0[s] = *(const short8*)&s_seq[col * SEQ_STRIDE + l0 * CINP + 32 * s + quad * 8];
            af1[s] = *(const short8*)&s_seq[col * SEQ_STRIDE + l1 * CINP + 32 * s + quad * 8];
        }
        f32x4 cacc0 = {0.f,0.f,0.f,0.f};
        f32x4 cacc1 = {0.f,0.f,0.f,0.f};
        #pragma unroll
        for (int s = 0; s < 7; s++) {
            cacc0 = __builtin_amdgcn_mfma_f32_16x16x32_bf16(wb[s], af0[s], cacc0, 0, 0, 0);
            cacc1 = __builtin_amdgcn_mfma_f32_16x16x32_bf16(wb[s], af1[s], cacc1, 0, 0, 0);
        }
        // ---- epilogue: lane holds batch=col, f = 16*wave + 4q + r ----
        float a0 = fmaxf(cacc0[0] + cbias[0], 0.0f);
        float a1 = fmaxf(cacc0[1] + cbias[1], 0.0f);
        float a2 = fmaxf(cacc0[2] + cbias[2], 0.0f);
        float a3 = fmaxf(cacc0[3] + cbias[3], 0.0f);
        float e0 = fmaxf(cacc1[0] + cbias[0], 0.0f);
        float e1 = fmaxf(cacc1[1] + cbias[1], 0.0f);
        float e2 = fmaxf(cacc1[2] + cbias[2], 0.0f);
        float e3 = fmaxf(cacc1[3] + cbias[3], 0.0f);
        {
            float cm0 = (l0 >= 10 + plen_lane && l0 < 20 + plen_lane) ? 1.0f : 0.0f;
            float cm1 = (l1 >= 10 + plen_lane && l1 < 20 + plen_lane) ? 1.0f : 0.0f;
            if (l0 < 10) {            // wave-uniform
                sum_n[0] += a0; sum_n[1] += a1; sum_n[2] += a2; sum_n[3] += a3;
            }
            if (l1 < 10) {
                sum_n[0] += e0; sum_n[1] += e1; sum_n[2] += e2; sum_n[3] += e3;
            }
            sum_c[0] += cm0 * a0 + cm1 * e0;
            sum_c[1] += cm0 * a1 + cm1 * e1;
            sum_c[2] += cm0 * a2 + cm1 * e2;
            sum_c[3] += cm0 * a3 + cm1 * e3;
        }

        // ---- MLP section: only for l whose y is consumed (l in [10,25]) ----
        if (l0 >= 10 && l0 < 26) {           // block-uniform; barrier inside is legal
            ushort4 pk0 = { bf16bits(a0), bf16bits(a1), bf16bits(a2), bf16bits(a3) };
            ushort4 pk1 = { bf16bits(e0), bf16bits(e1), bf16bits(e2), bf16bits(e3) };
            *(ushort4*)&s_tile[l0 & 3][col * TILE_STRIDE + wave * 16 + 4 * quad] = pk0;
            *(ushort4*)&s_tile[l1 & 3][col * TILE_STRIDE + wave * 16 + 4 * quad] = pk1;
            __syncthreads();   // conv tiles written -> MLP may read; ring WAR fence

            // ---- MLP layer1 GEMM: D[m=batch][n = wave's 16-n tile], K = 128 f ----
            short8 am0[4], am1[4];
            #pragma unroll
            for (int s = 0; s < 4; s++) {
                am0[s] = *(const short8*)&s_tile[l0 & 3][col * TILE_STRIDE + 32 * s + quad * 8];
                am1[s] = *(const short8*)&s_tile[l1 & 3][col * TILE_STRIDE + 32 * s + quad * 8];
            }
            f32x4 hacc0 = {0.f,0.f,0.f,0.f};
            f32x4 hacc1 = {0.f,0.f,0.f,0.f};
            #pragma unroll
            for (int s = 0; s < 4; s++) {
                hacc0 = __builtin_amdgcn_mfma_f32_16x16x32_bf16(am0[s], w1b[s], hacc0, 0, 0, 0);
                hacc1 = __builtin_amdgcn_mfma_f32_16x16x32_bf16(am1[s], w1b[s], hacc1, 0, 0, 0);
            }
            // ---- y partial = relu(h+b1) @ w2 over this wave's 16 n; DPP row-sum ----
            float p0[4], p1[4];
            #pragma unroll
            for (int r = 0; r < 4; r++) {
                p0[r] = row_sum16(fmaxf(hacc0[r] + b1v, 0.f) * w2v);
                p1[r] = row_sum16(fmaxf(hacc1[r] + b1v, 0.f) * w2v);
            }
            if (col == 0) {                  // batch index = 4*quad + r
                *(f32x4*)&s_yp[(l0 - 10) * YP_STRIDE + wave * 16 + quad * 4] =
                    (f32x4){p0[0], p0[1], p0[2], p0[3]};
                *(f32x4*)&s_yp[(l1 - 10) * YP_STRIDE + wave * 16 + quad * 4] =
                    (f32x4){p1[0], p1[1], p1[2], p1[3]};
            }
        }
    }
    __syncthreads();   // all s_seq reads done -> overlay safe; s_yp complete

    // ---- flank-average partials: apply navg_w/cavg_w post-loop ----
    {
        float an = 0.f, ac = 0.f;
        #pragma unroll
        for (int r = 0; r < 4; r++) {
            int fidx = wave * 16 + 4 * quad + r;
            an += sum_n[r] * navg_w[fidx];
            ac += sum_c[r] * cavg_w[fidx];
        }
        an += __shfl_xor(an, 16); an += __shfl_xor(an, 32);   // sum over quads
        ac += __shfl_xor(ac, 16); ac += __shfl_xor(ac, 32);
        if (quad == 0) {                     // lane < 16: one per batch
            s_avg[wave * 2 * GB + 0 * GB + col] = an;
            s_avg[wave * 2 * GB + 1 * GB + col] = ac;
        }
    }
    __syncthreads();

    // ---- y finalize: y = tanh(sum of 4 wave-partials + b2), l in [10,25] (512 vals) ----
    // m-fastest decomposition: 64 lanes cover all 32 banks 2-way (conflict-free);
    // YP_STRIDE=136 decorrelates the per-l bank offset (136%32 = 8).
    {
        const float bn = n_b2[0], bc = c_b2[0];
        for (int i = t; i < 2 * GB * NYL; i += 512) {
            int m = i & 15, rem = i >> 4;        // rem = 0..31
            int li = rem & 15, hd = rem >> 4;    // li = l-10
            float v = (hd ? bc : bn);
            #pragma unroll
            for (int w = 0; w < 4; w++)
                v += s_yp[li * YP_STRIDE + (hd * 4 + w) * 16 + m];
            s_y[hd * GB * 36 + m * 36 + (10 + li)] = tanhf(v);
        }
    }
    __syncthreads();

    // ---- final combine: one thread per batch row ----
    if (t < GB) {
        const int m = t;
        const int plen = plen_arr[b0 + m];
        const float* ym = s_y + m * 36;               // n-head row
        const float* yc = s_y + GB * 36 + m * 36;     // c-head row
        float cleaved_n = ym[10];
        float mn = 0.f;   // reference maxes (y+1)*mask over ALL l; unmasked give 0
        for (int l = 11; l < 10 + plen; l++) mn = fmaxf(mn, ym[l] + 1.f);
        float maxpool_n = -(mn - 1.f);
        float cleaved_c = yc[10 + plen - 1];
        float mc = 0.f;
        for (int l = 10; l < 10 + plen - 1; l++) mc = fmaxf(mc, yc[l] + 1.f);
        float maxpool_c = -(mc - 1.f);
        float sn = 0.f, sc = 0.f;
        #pragma unroll
        for (int w = 0; w < 8; w++) {
            sn += s_avg[w * 2 * GB + 0 * GB + m];
            sc += s_avg[w * 2 * GB + 1 * GB + m];
        }
        float avg_n = tanhf(sn * 0.1f + navg_b[0]);
        float avg_c = tanhf(sc * 0.1f + cavg_b[0]);
        float comb = cleaved_n * out_w[0] + maxpool_n * out_w[1] + avg_n * out_w[2]
                   + cleaved_c * out_w[3] + maxpool_c * out_w[4] + avg_c * out_w[5]
                   + out_b[0];
        out[b0 + m] = 1.f / (1.f + expf(-comb));
    }
}

extern "C" void kernel_launch(void* const* d_in, const int* in_sizes, int n_in,
                              void* d_out, int out_size, void* d_ws, size_t ws_size,
                              hipStream_t stream) {
    const int B = in_sizes[1];
    fused_kernel<<<B / GB, 512, 0, stream>>>(
        (const float*)d_in[0],  (const int*)d_in[1],
        (const float*)d_in[2],  (const float*)d_in[3],
        (const float*)d_in[4],  (const float*)d_in[5],
        (const float*)d_in[6],  (const float*)d_in[7],
        (const float*)d_in[8],  (const float*)d_in[9],
        (const float*)d_in[10], (const float*)d_in[11],
        (const float*)d_in[12], (const float*)d_in[13],
        (const float*)d_in[14], (const float*)d_in[15],
        (const float*)d_in[16], (const float*)d_in[17],
        (float*)d_out);
}